// Round 2
// baseline (521.116 us; speedup 1.0000x reference)
//
#include <hip/hip_runtime.h>
#include <stdint.h>

// DP_Attention: B=8, S=4096, D=K=1024, fp32.
// Decomposition:
//   fq = q@Wq+bq                         (tiny)
//   g[b] = Wk @ fq[b], cb[b]=fq[b].bk    (kills the k@Wk GEMM: logits = g.k_s + cb)
//   attn = sigmoid((g.k_s+cb)/32)        (streaming, 128 MB)
//   norm2[b,s] = ||v_s@Wv + bv||^2       (the one real GEMM, bf16 MFMA 16x16x32,
//                                         128x128x32 tiles, swizzled LDS)
//   y[b] = sum_s coef_s v_s, csum=sum coef   (streaming, 128 MB, fp32)
//   seed = y@Wv + csum*bv + 0.1*noise
// Noise = JAX threefry, PARTITIONABLE scheme (jax>=0.4.36 default):
//   bits[i] = o0^o1 of threefry2x32(key=(0,1234), x=(i>>32, i&0xffffffff))

#define Bn 8
#define Sn 4096
#define Dn 1024
#define Kn 1024

typedef unsigned short u16;
typedef __attribute__((ext_vector_type(4))) unsigned short u16x4;
typedef __attribute__((ext_vector_type(8))) unsigned short u16x8;
typedef __attribute__((ext_vector_type(8))) __bf16 bf16x8;
typedef __attribute__((ext_vector_type(4))) float f32x4;

__device__ __forceinline__ u16 f2bf(float f) {
  uint32_t x = __float_as_uint(f);
  x += 0x7FFFu + ((x >> 16) & 1u);   // RNE
  return (u16)(x >> 16);
}

// ---------------- JAX threefry2x32 (key1=0, key2=1234) ----------------
__device__ __forceinline__ uint32_t rotl32(uint32_t x, int d) {
  return (x << d) | (x >> (32 - d));
}
__device__ void threefry2x32(uint32_t k0, uint32_t k1, uint32_t x0, uint32_t x1,
                             uint32_t* o0, uint32_t* o1) {
  uint32_t ks0 = k0, ks1 = k1, ks2 = k0 ^ k1 ^ 0x1BD11BDAu;
  x0 += ks0; x1 += ks1;
#define TF_R4(a,b,c,d) \
  x0 += x1; x1 = rotl32(x1,a); x1 ^= x0; \
  x0 += x1; x1 = rotl32(x1,b); x1 ^= x0; \
  x0 += x1; x1 = rotl32(x1,c); x1 ^= x0; \
  x0 += x1; x1 = rotl32(x1,d); x1 ^= x0;
  TF_R4(13,15,26,6);  x0 += ks1; x1 += ks2 + 1u;
  TF_R4(17,29,16,24); x0 += ks2; x1 += ks0 + 2u;
  TF_R4(13,15,26,6);  x0 += ks0; x1 += ks1 + 3u;
  TF_R4(17,29,16,24); x0 += ks1; x1 += ks2 + 4u;
  TF_R4(13,15,26,6);  x0 += ks2; x1 += ks0 + 5u;
#undef TF_R4
  *o0 = x0; *o1 = x1;
}

// XLA ErfInv32 (Giles polynomial)
__device__ float erfinv_f(float x) {
  float w = -log1pf(-x * x);
  float p;
  if (w < 5.0f) {
    w -= 2.5f;
    p = 2.81022636e-08f;
    p = fmaf(p, w, 3.43273939e-07f);
    p = fmaf(p, w, -3.5233877e-06f);
    p = fmaf(p, w, -4.39150654e-06f);
    p = fmaf(p, w, 0.00021858087f);
    p = fmaf(p, w, -0.00125372503f);
    p = fmaf(p, w, -0.00417768164f);
    p = fmaf(p, w, 0.246640727f);
    p = fmaf(p, w, 1.50140941f);
  } else {
    w = sqrtf(w) - 3.0f;
    p = -0.000200214257f;
    p = fmaf(p, w, 0.000100950558f);
    p = fmaf(p, w, 0.00134934322f);
    p = fmaf(p, w, -0.00367342844f);
    p = fmaf(p, w, 0.00573950773f);
    p = fmaf(p, w, -0.0076224613f);
    p = fmaf(p, w, 0.00943887047f);
    p = fmaf(p, w, 1.00167406f);
    p = fmaf(p, w, 2.83297682f);
  }
  return p * x;
}

// ---------------- small kernels ----------------
__global__ void k_fq(const float* __restrict__ q, const float* __restrict__ wq,
                     const float* __restrict__ bq, float* __restrict__ fq) {
  int t = blockIdx.x * 256 + threadIdx.x;   // 8192
  int b = t >> 10, j = t & 1023;
  const float* qb = q + b * Dn;
  float acc = 0.f;
  for (int d = 0; d < Dn; ++d) acc = fmaf(qb[d], wq[d * Kn + j], acc);
  fq[t] = acc + bq[j];
}

__global__ void k_g(const float* __restrict__ wk, const float* __restrict__ fq,
                    float* __restrict__ g) {
  int wid = (blockIdx.x * 256 + threadIdx.x) >> 6;   // 8192 waves
  int lane = threadIdx.x & 63;
  int b = wid >> 10, d = wid & 1023;
  const float* row = wk + d * Kn;
  const float* f = fq + b * Kn;
  float acc = 0.f;
  for (int j = lane; j < Kn; j += 64) acc = fmaf(row[j], f[j], acc);
  for (int m = 32; m; m >>= 1) acc += __shfl_xor(acc, m, 64);
  if (lane == 0) g[b * Dn + d] = acc;
}

__global__ void k_cb(const float* __restrict__ fq, const float* __restrict__ bk,
                     float* __restrict__ cb) {
  int b = threadIdx.x >> 6;
  int lane = threadIdx.x & 63;
  float acc = 0.f;
  for (int j = lane; j < Kn; j += 64) acc = fmaf(fq[b * Kn + j], bk[j], acc);
  for (int m = 32; m; m >>= 1) acc += __shfl_xor(acc, m, 64);
  if (lane == 0) cb[b] = acc;
}

// Wv (fp32 [k][n]) -> WvT_tiled bf16 [kb][n][kk], kb=k/32, kk=k%32
__global__ void k_twv(const float* __restrict__ wv, u16* __restrict__ wvt) {
  int t = blockIdx.x * 256 + threadIdx.x;  // 262144
  int k = t >> 8, n4 = (t & 255) * 4;
  int kb = k >> 5, kk = k & 31;
  float4 vv = *reinterpret_cast<const float4*>(wv + k * Kn + n4);
  u16* dst = wvt + kb * (1024 * 32) + n4 * 32 + kk;
  dst[0]  = f2bf(vv.x);
  dst[32] = f2bf(vv.y);
  dst[64] = f2bf(vv.z);
  dst[96] = f2bf(vv.w);
}

__global__ void k_attn(const float* __restrict__ kmat, const float* __restrict__ g,
                       const float* __restrict__ cb, float* __restrict__ out_attn) {
  int row = blockIdx.x * 4 + (threadIdx.x >> 6);  // 32768
  int lane = threadIdx.x & 63;
  int b = row >> 12;
  const float4* kr = reinterpret_cast<const float4*>(kmat + (size_t)row * Dn);
  const float4* gr = reinterpret_cast<const float4*>(g + b * Dn);
  float acc = 0.f;
#pragma unroll
  for (int i = 0; i < 4; ++i) {
    float4 kv = kr[lane + 64 * i];
    float4 gv = gr[lane + 64 * i];
    acc = fmaf(kv.x, gv.x, acc); acc = fmaf(kv.y, gv.y, acc);
    acc = fmaf(kv.z, gv.z, acc); acc = fmaf(kv.w, gv.w, acc);
  }
  for (int m = 32; m; m >>= 1) acc += __shfl_xor(acc, m, 64);
  if (lane == 0) {
    float logit = (acc + cb[b]) * 0.03125f;  // 1/sqrt(1024)
    out_attn[row] = 1.f / (1.f + expf(-logit));
  }
}

// ---------------- main GEMM: norm2[b,s] = ||v_s@Wv + bv||^2 ----------------
#define BM 128
#define BN 128
#define BK 32

__global__ __launch_bounds__(256)
void k_norm2(const float* __restrict__ v, const u16* __restrict__ wvt,
             const float* __restrict__ bv, float* __restrict__ norm2) {
  int blk = blockIdx.x;          // 2048; sb fastest for per-XCD L2 reuse of v rows
  int b  = blk >> 8;
  int nb = (blk >> 5) & 7;
  int sb = blk & 31;
  int s0 = sb * BM;
  int n0 = nb * BN;

  __shared__ u16 As[BM * 40];    // [r][kk], stride 40 (pad: conflict-free A reads)
  __shared__ u16 Bs[BN * 32];    // [n][kk], kk-block XOR-swizzled
  __shared__ float nrm[BM];

  int tid = threadIdx.x;
  int wave = tid >> 6, lane = tid & 63;
  int wr = wave & 1, wc = wave >> 1;   // wave tile: rows wr*64.., cols wc*64..
  int m = lane & 15, q = lane >> 4;

  f32x4 acc[4][4];
#pragma unroll
  for (int i = 0; i < 4; ++i)
#pragma unroll
    for (int j = 0; j < 4; ++j) acc[i][j] = (f32x4){0.f, 0.f, 0.f, 0.f};

  if (tid < BM) nrm[tid] = 0.f;

  const float* vbase = v + ((size_t)b * Sn + s0) * Dn;

  for (int k0 = 0; k0 < Dn; k0 += BK) {
    __syncthreads();
    // stage A: 128x32 fp32 -> bf16 (16 elems/thread)
#pragma unroll
    for (int i = 0; i < 4; ++i) {
      int flat = (i * 256 + tid) * 4;          // 0..16380
      int r = flat >> 5, kk = flat & 31;
      float4 vv = *reinterpret_cast<const float4*>(vbase + r * Dn + k0 + kk);
      u16x4 pk = { f2bf(vv.x), f2bf(vv.y), f2bf(vv.z), f2bf(vv.w) };
      *reinterpret_cast<u16x4*>(&As[r * 40 + kk]) = pk;
    }
    // stage B: 8KB slab of pre-transposed bf16 Wv (32 B/thread), XOR swizzle
    {
      int kb = k0 >> 5;
      const u16* slab = wvt + kb * (1024 * 32) + n0 * 32;
#pragma unroll
      for (int i = 0; i < 2; ++i) {
        int idx16 = i * 256 + tid;             // 0..511
        int n = idx16 >> 2, qq = idx16 & 3;
        uint4 d = *reinterpret_cast<const uint4*>(slab + idx16 * 8);
        int qsw = qq ^ ((n >> 1) & 3);
        *reinterpret_cast<uint4*>(&Bs[n * 32 + qsw * 8]) = d;
      }
    }
    __syncthreads();

    bf16x8 a[4], bb[4];
#pragma unroll
    for (int rt = 0; rt < 4; ++rt) {
      int r = wr * 64 + rt * 16 + m;
      u16x8 raw = *reinterpret_cast<const u16x8*>(&As[r * 40 + q * 8]);
      a[rt] = __builtin_bit_cast(bf16x8, raw);
    }
#pragma unroll
    for (int ct = 0; ct < 4; ++ct) {
      int n = wc * 64 + ct * 16 + m;
      int qsw = q ^ ((n >> 1) & 3);
      u16x8 raw = *reinterpret_cast<const u16x8*>(&Bs[n * 32 + qsw * 8]);
      bb[ct] = __builtin_bit_cast(bf16x8, raw);
    }
#pragma unroll
    for (int rt = 0; rt < 4; ++rt)
#pragma unroll
      for (int ct = 0; ct < 4; ++ct)
        acc[rt][ct] = __builtin_amdgcn_mfma_f32_16x16x32_bf16(a[rt], bb[ct],
                                                              acc[rt][ct], 0, 0, 0);
  }

  // epilogue: row-wise sum of squares (C/D layout: col=lane&15, row=q*4+reg)
  float bvv[4];
#pragma unroll
  for (int ct = 0; ct < 4; ++ct) bvv[ct] = bv[n0 + wc * 64 + ct * 16 + m];

#pragma unroll
  for (int rt = 0; rt < 4; ++rt) {
#pragma unroll
    for (int reg = 0; reg < 4; ++reg) {
      float ss = 0.f;
#pragma unroll
      for (int ct = 0; ct < 4; ++ct) {
        float f = acc[rt][ct][reg] + bvv[ct];
        ss = fmaf(f, f, ss);
      }
      ss += __shfl_xor(ss, 1, 64);
      ss += __shfl_xor(ss, 2, 64);
      ss += __shfl_xor(ss, 4, 64);
      ss += __shfl_xor(ss, 8, 64);
      if (m == 0) {
        int r = wr * 64 + rt * 16 + q * 4 + reg;
        atomicAdd(&nrm[r], ss);
      }
    }
  }
  __syncthreads();
  if (tid < BM) atomicAdd(&norm2[b * Sn + s0 + tid], nrm[tid]);
}

// ---------------- y[b,d] = sum_s coef_s * v[b,s,d]; csum[b] = sum coef ----------------
__global__ void k_wsum(const float* __restrict__ v, const float* __restrict__ attn,
                       const float* __restrict__ norm2, float* __restrict__ y,
                       float* __restrict__ csum) {
  int blk = blockIdx.x;         // 256
  int b = blk >> 5;
  int sc = (blk & 31) * 128;
  __shared__ float coef[128];
  int tid = threadIdx.x;
  if (tid < 128) {
    int s = sc + tid;
    float nm = sqrtf(norm2[b * Sn + s]);
    coef[tid] = attn[b * Sn + s] / fmaxf(1.f, nm);
  }
  __syncthreads();
  if (tid == 0) {
    float cs = 0.f;
    for (int i = 0; i < 128; ++i) cs += coef[i];
    atomicAdd(&csum[b], cs);
  }
  const float* vb = v + ((size_t)b * Sn + sc) * Dn;
  int d0 = tid * 4;
  float a0 = 0.f, a1 = 0.f, a2 = 0.f, a3 = 0.f;
  for (int i = 0; i < 128; ++i) {
    float c = coef[i];
    float4 vv = *reinterpret_cast<const float4*>(vb + i * Dn + d0);
    a0 = fmaf(c, vv.x, a0); a1 = fmaf(c, vv.y, a1);
    a2 = fmaf(c, vv.z, a2); a3 = fmaf(c, vv.w, a3);
  }
  atomicAdd(&y[b * Dn + d0 + 0], a0);
  atomicAdd(&y[b * Dn + d0 + 1], a1);
  atomicAdd(&y[b * Dn + d0 + 2], a2);
  atomicAdd(&y[b * Dn + d0 + 3], a3);
}

// ---------------- seed = y@Wv + csum*bv + 0.1*noise ----------------
__global__ void k_seed(const float* __restrict__ y, const float* __restrict__ wv,
                       const float* __restrict__ bv, const float* __restrict__ csum,
                       float* __restrict__ out_seed) {
  int t = blockIdx.x * 256 + threadIdx.x;  // 8192
  int b = t >> 10, j = t & 1023;
  const float* yb = y + b * Dn;
  float acc = 0.f;
  for (int d = 0; d < Dn; ++d) acc = fmaf(yb[d], wv[d * Kn + j], acc);
  acc += csum[b] * bv[j];

  // JAX noise, partitionable threefry (modern default):
  //   count64 = t; (x0,x1) = (hi,lo) = (0,t); bits = o0 ^ o1
  uint32_t o0, o1;
  threefry2x32(0u, 1234u, 0u, (uint32_t)t, &o0, &o1);
  uint32_t bits = o0 ^ o1;
  float f = __uint_as_float((bits >> 9) | 0x3F800000u) - 1.0f;
  float lo = __uint_as_float(0xBF7FFFFFu);     // nextafter(-1,0)
  float u = f * (1.0f - lo) + lo;
  u = fmaxf(u, lo);
  float nz = 1.41421356237f * erfinv_f(u);
  out_seed[t] = acc + nz * 0.1f;
}

extern "C" void kernel_launch(void* const* d_in, const int* in_sizes, int n_in,
                              void* d_out, int out_size, void* d_ws, size_t ws_size,
                              hipStream_t stream) {
  const float* q  = (const float*)d_in[0];
  const float* k  = (const float*)d_in[1];
  const float* v  = (const float*)d_in[2];
  const float* wq = (const float*)d_in[3];
  const float* bq = (const float*)d_in[4];
  const float* wk = (const float*)d_in[5];
  const float* bk = (const float*)d_in[6];
  const float* wv = (const float*)d_in[7];
  const float* bv = (const float*)d_in[8];
  float* out = (float*)d_out;
  float* ws = (float*)d_ws;

  // ws layout (floats): fq[0,8192) g[8192,16384) cb[16384,16392)
  //                     norm2[16896,49664) y[49664,57856) csum[57856,57864)
  //                     wvt: bytes [262144, 262144+2MB)
  float* fq    = ws;
  float* g     = ws + 8192;
  float* cb    = ws + 16384;
  float* norm2 = ws + 16896;
  float* y     = ws + 49664;
  float* csum  = ws + 57856;
  u16* wvt = (u16*)((char*)d_ws + 262144);

  hipMemsetAsync(norm2, 0, (32768 + 8192 + 8) * sizeof(float), stream);
  k_fq  <<<32,   256, 0, stream>>>(q, wq, bq, fq);
  k_twv <<<1024, 256, 0, stream>>>(wv, wvt);
  k_g   <<<2048, 256, 0, stream>>>(wk, fq, g);
  k_cb  <<<1,    512, 0, stream>>>(fq, bk, cb);
  k_attn<<<8192, 256, 0, stream>>>(k, g, cb, out + 8192);
  k_norm2<<<2048,256, 0, stream>>>(v, wvt, bv, norm2);
  k_wsum<<<256,  256, 0, stream>>>(v, out + 8192, norm2, y, csum);
  k_seed<<<32,   256, 0, stream>>>(y, wv, bv, csum, out);
}

// Round 3
// 434.148 us; speedup vs baseline: 1.2003x; 1.2003x over previous
//
#include <hip/hip_runtime.h>
#include <stdint.h>

// DP_Attention: B=8, S=4096, D=K=1024, fp32.
//   fq = q@Wq+bq (split-K matvec) ; g[b]=Wk@fq[b], cb[b]=fq.bk
//   attn = sigmoid((g.k_s+cb)/32)            (stream k, 134 MB)
//   vb = bf16(v)                             (stream, enables global_load_lds GEMM)
//   norm2[b,s] = ||v_s@Wv + bv||^2           (m97-style MFMA GEMM, BK=64,
//                                             global_load_lds + src-side XOR swizzle)
//   y[b] = sum_s coef_s v_s (from vb), csum  (stream vb, L3-hot)
//   seed = y@Wv + csum*bv + 0.1*noise        (split-K + threefry partitionable)

#define Bn 8
#define Sn 4096
#define Dn 1024
#define Kn 1024

typedef unsigned short u16;
typedef __attribute__((ext_vector_type(4))) unsigned short u16x4;
typedef __attribute__((ext_vector_type(8))) unsigned short u16x8;
typedef __attribute__((ext_vector_type(8))) __bf16 bf16x8;
typedef __attribute__((ext_vector_type(4))) float f32x4;

__device__ __forceinline__ u16 f2bf(float f) {
  uint32_t x = __float_as_uint(f);
  x += 0x7FFFu + ((x >> 16) & 1u);   // RNE
  return (u16)(x >> 16);
}
__device__ __forceinline__ float bf2f(u16 h) {
  return __uint_as_float(((uint32_t)h) << 16);
}

// ---------------- JAX threefry2x32 (key=(0,1234)), partitionable ----------------
__device__ __forceinline__ uint32_t rotl32(uint32_t x, int d) {
  return (x << d) | (x >> (32 - d));
}
__device__ void threefry2x32(uint32_t k0, uint32_t k1, uint32_t x0, uint32_t x1,
                             uint32_t* o0, uint32_t* o1) {
  uint32_t ks0 = k0, ks1 = k1, ks2 = k0 ^ k1 ^ 0x1BD11BDAu;
  x0 += ks0; x1 += ks1;
#define TF_R4(a,b,c,d) \
  x0 += x1; x1 = rotl32(x1,a); x1 ^= x0; \
  x0 += x1; x1 = rotl32(x1,b); x1 ^= x0; \
  x0 += x1; x1 = rotl32(x1,c); x1 ^= x0; \
  x0 += x1; x1 = rotl32(x1,d); x1 ^= x0;
  TF_R4(13,15,26,6);  x0 += ks1; x1 += ks2 + 1u;
  TF_R4(17,29,16,24); x0 += ks2; x1 += ks0 + 2u;
  TF_R4(13,15,26,6);  x0 += ks0; x1 += ks1 + 3u;
  TF_R4(17,29,16,24); x0 += ks1; x1 += ks2 + 4u;
  TF_R4(13,15,26,6);  x0 += ks2; x1 += ks0 + 5u;
#undef TF_R4
  *o0 = x0; *o1 = x1;
}

__device__ float erfinv_f(float x) {
  float w = -log1pf(-x * x);
  float p;
  if (w < 5.0f) {
    w -= 2.5f;
    p = 2.81022636e-08f;
    p = fmaf(p, w, 3.43273939e-07f);
    p = fmaf(p, w, -3.5233877e-06f);
    p = fmaf(p, w, -4.39150654e-06f);
    p = fmaf(p, w, 0.00021858087f);
    p = fmaf(p, w, -0.00125372503f);
    p = fmaf(p, w, -0.00417768164f);
    p = fmaf(p, w, 0.246640727f);
    p = fmaf(p, w, 1.50140941f);
  } else {
    w = sqrtf(w) - 3.0f;
    p = -0.000200214257f;
    p = fmaf(p, w, 0.000100950558f);
    p = fmaf(p, w, 0.00134934322f);
    p = fmaf(p, w, -0.00367342844f);
    p = fmaf(p, w, 0.00573950773f);
    p = fmaf(p, w, -0.0076224613f);
    p = fmaf(p, w, 0.00943887047f);
    p = fmaf(p, w, 1.00167406f);
    p = fmaf(p, w, 2.83297682f);
  }
  return p * x;
}

// ---------------- fq = q@Wq + bq, split-K (256 blocks) ----------------
__global__ void k_fq(const float* __restrict__ q, const float* __restrict__ wq,
                     const float* __restrict__ bq, float* __restrict__ fq) {
  int blk = blockIdx.x;               // b(8) x jc(4) x dc(8)
  int b = blk >> 5, jc = (blk >> 3) & 3, dc = blk & 7;
  int j = jc * 256 + threadIdx.x;
  const float* qb = q + b * Dn;
  float acc = 0.f;
  int d0 = dc * 128;
  for (int d = d0; d < d0 + 128; ++d)
    acc = fmaf(qb[d], wq[(size_t)d * Kn + j], acc);
  if (dc == 0) acc += bq[j];
  atomicAdd(&fq[b * Kn + j], acc);
}

__global__ void k_g(const float* __restrict__ wk, const float* __restrict__ fq,
                    float* __restrict__ g) {
  int wid = (blockIdx.x * 256 + threadIdx.x) >> 6;   // 8192 waves
  int lane = threadIdx.x & 63;
  int b = wid >> 10, d = wid & 1023;
  const float* row = wk + (size_t)d * Kn;
  const float* f = fq + b * Kn;
  float acc = 0.f;
  for (int j = lane; j < Kn; j += 64) acc = fmaf(row[j], f[j], acc);
  for (int m = 32; m; m >>= 1) acc += __shfl_xor(acc, m, 64);
  if (lane == 0) g[b * Dn + d] = acc;
}

__global__ void k_cb(const float* __restrict__ fq, const float* __restrict__ bk,
                     float* __restrict__ cb) {
  int b = threadIdx.x >> 6;
  int lane = threadIdx.x & 63;
  float acc = 0.f;
  for (int j = lane; j < Kn; j += 64) acc = fmaf(fq[b * Kn + j], bk[j], acc);
  for (int m = 32; m; m >>= 1) acc += __shfl_xor(acc, m, 64);
  if (lane == 0) cb[b] = acc;
}

// ---------------- Wv fp32 [k][n] -> wvt bf16 [n][k] (LDS 64x64 transpose) --------
__global__ void k_twv(const float* __restrict__ wv, u16* __restrict__ wvt) {
  __shared__ u16 tile[64][72];
  int k0 = (blockIdx.x & 15) * 64, n0 = (blockIdx.x >> 4) * 64;
  int tid = threadIdx.x;
  int r = tid >> 2, c0 = (tid & 3) * 16;
#pragma unroll
  for (int i = 0; i < 4; ++i) {
    float4 vv = *reinterpret_cast<const float4*>(wv + (size_t)(k0 + r) * Kn + n0 + c0 + i * 4);
    tile[r][c0 + i * 4 + 0] = f2bf(vv.x);
    tile[r][c0 + i * 4 + 1] = f2bf(vv.y);
    tile[r][c0 + i * 4 + 2] = f2bf(vv.z);
    tile[r][c0 + i * 4 + 3] = f2bf(vv.w);
  }
  __syncthreads();
  int n = tid >> 2, kc = (tid & 3) * 16;
  alignas(16) u16 o[16];
#pragma unroll
  for (int i = 0; i < 16; ++i) o[i] = tile[kc + i][n];
  *reinterpret_cast<u16x8*>(wvt + (size_t)(n0 + n) * Kn + k0 + kc)     = *reinterpret_cast<u16x8*>(&o[0]);
  *reinterpret_cast<u16x8*>(wvt + (size_t)(n0 + n) * Kn + k0 + kc + 8) = *reinterpret_cast<u16x8*>(&o[8]);
}

// ---------------- v fp32 -> vb bf16 (row-major) ----------------
__global__ void k_tv(const float* __restrict__ v, u16* __restrict__ vb) {
  size_t t = (size_t)blockIdx.x * 256 + threadIdx.x;   // 4194304
  const float4* p = reinterpret_cast<const float4*>(v + t * 8);
  float4 a = p[0], b = p[1];
  u16x8 o = { f2bf(a.x), f2bf(a.y), f2bf(a.z), f2bf(a.w),
              f2bf(b.x), f2bf(b.y), f2bf(b.z), f2bf(b.w) };
  *reinterpret_cast<u16x8*>(vb + t * 8) = o;
}

// ---------------- attn = sigmoid((g.k_s + cb)/32) ----------------
__global__ void k_attn(const float* __restrict__ kmat, const float* __restrict__ g,
                       const float* __restrict__ cb, float* __restrict__ out_attn) {
  int row = blockIdx.x * 4 + (threadIdx.x >> 6);  // 32768
  int lane = threadIdx.x & 63;
  int b = row >> 12;
  const float4* kr = reinterpret_cast<const float4*>(kmat + (size_t)row * Dn);
  const float4* gr = reinterpret_cast<const float4*>(g + b * Dn);
  float acc = 0.f;
#pragma unroll
  for (int i = 0; i < 4; ++i) {
    float4 kv = kr[lane + 64 * i];
    float4 gv = gr[lane + 64 * i];
    acc = fmaf(kv.x, gv.x, acc); acc = fmaf(kv.y, gv.y, acc);
    acc = fmaf(kv.z, gv.z, acc); acc = fmaf(kv.w, gv.w, acc);
  }
  for (int m = 32; m; m >>= 1) acc += __shfl_xor(acc, m, 64);
  if (lane == 0) {
    float logit = (acc + cb[b]) * 0.03125f;
    out_attn[row] = 1.f / (1.f + expf(-logit));
  }
}

// ---------------- norm2 GEMM: m97 structure, BK=64, global_load_lds ----------------
// LDS layout: row r (128 B = 8 chunks of 16 B), chunk c stored at pos c^(r&7).
// Swizzle applied on the SOURCE side: lane i of stage-inst u fetches
// row u*8+(i>>3), chunk (i&7)^(i>>3); HW scatters to base+i*16.
__global__ __launch_bounds__(256)
void k_norm2(const u16* __restrict__ vb, const u16* __restrict__ wvt,
             const float* __restrict__ bv, float* __restrict__ norm2) {
  int blk = blockIdx.x;          // 2048: b(8) x nb(8) x sb(32), sb fastest
  int b  = blk >> 8;
  int nb = (blk >> 5) & 7;
  int sb = blk & 31;
  int s0 = sb * 128, n0 = nb * 128;

  __shared__ u16 As[128 * 64];
  __shared__ u16 Bs[128 * 64];
  __shared__ float nrm[128];

  int tid = threadIdx.x;
  int wave = tid >> 6, lane = tid & 63;
  int wr = wave & 1, wc = wave >> 1;
  int m = lane & 15, q = lane >> 4;

  f32x4 acc[4][4];
#pragma unroll
  for (int i = 0; i < 4; ++i)
#pragma unroll
    for (int j = 0; j < 4; ++j) acc[i][j] = (f32x4){0.f, 0.f, 0.f, 0.f};
  if (tid < 128) nrm[tid] = 0.f;

  int lrow = lane >> 3;                 // 0..7
  int lchunk = (lane & 7) ^ lrow;       // source chunk for this lane
  const u16* gA0 = vb  + ((size_t)(b * Sn + s0) + lrow) * 1024 + lchunk * 8;
  const u16* gB0 = wvt + ((size_t)(n0 + lrow)) * 1024 + lchunk * 8;

  for (int k0 = 0; k0 < 1024; k0 += 64) {
    __syncthreads();
#pragma unroll
    for (int t = 0; t < 4; ++t) {
      int u = wave * 4 + t;
      __builtin_amdgcn_global_load_lds(
          (const __attribute__((address_space(1))) void*)(gA0 + (size_t)u * 8 * 1024 + k0),
          (__attribute__((address_space(3))) void*)(&As[u * 512]), 16, 0, 0);
      __builtin_amdgcn_global_load_lds(
          (const __attribute__((address_space(1))) void*)(gB0 + (size_t)u * 8 * 1024 + k0),
          (__attribute__((address_space(3))) void*)(&Bs[u * 512]), 16, 0, 0);
    }
    __syncthreads();

    bf16x8 a[4][2], bf[4][2];
#pragma unroll
    for (int rt = 0; rt < 4; ++rt) {
      int r = wr * 64 + rt * 16 + m;
#pragma unroll
      for (int j = 0; j < 2; ++j) {
        int c = j * 4 + q;
        u16x8 raw = *reinterpret_cast<const u16x8*>(&As[r * 64 + ((c ^ (r & 7)) * 8)]);
        a[rt][j] = __builtin_bit_cast(bf16x8, raw);
      }
    }
#pragma unroll
    for (int ct = 0; ct < 4; ++ct) {
      int n = wc * 64 + ct * 16 + m;
#pragma unroll
      for (int j = 0; j < 2; ++j) {
        int c = j * 4 + q;
        u16x8 raw = *reinterpret_cast<const u16x8*>(&Bs[n * 64 + ((c ^ (n & 7)) * 8)]);
        bf[ct][j] = __builtin_bit_cast(bf16x8, raw);
      }
    }
#pragma unroll
    for (int j = 0; j < 2; ++j)
#pragma unroll
      for (int rt = 0; rt < 4; ++rt)
#pragma unroll
        for (int ct = 0; ct < 4; ++ct)
          acc[rt][ct] = __builtin_amdgcn_mfma_f32_16x16x32_bf16(a[rt][j], bf[ct][j],
                                                                acc[rt][ct], 0, 0, 0);
  }

  // epilogue: row-wise sum of squares (C/D: col=lane&15, row=q*4+reg)
  float bvv[4];
#pragma unroll
  for (int ct = 0; ct < 4; ++ct) bvv[ct] = bv[n0 + wc * 64 + ct * 16 + m];

#pragma unroll
  for (int rt = 0; rt < 4; ++rt) {
#pragma unroll
    for (int reg = 0; reg < 4; ++reg) {
      float ss = 0.f;
#pragma unroll
      for (int ct = 0; ct < 4; ++ct) {
        float f = acc[rt][ct][reg] + bvv[ct];
        ss = fmaf(f, f, ss);
      }
      ss += __shfl_xor(ss, 1, 64);
      ss += __shfl_xor(ss, 2, 64);
      ss += __shfl_xor(ss, 4, 64);
      ss += __shfl_xor(ss, 8, 64);
      if (m == 0) {
        int r = wr * 64 + rt * 16 + q * 4 + reg;
        atomicAdd(&nrm[r], ss);
      }
    }
  }
  __syncthreads();
  if (tid < 128) atomicAdd(&norm2[b * Sn + s0 + tid], nrm[tid]);
}

// ---------------- y[b,d] = sum_s coef_s vb[b,s,d]; csum ----------------
__global__ void k_wsum(const u16* __restrict__ vb, const float* __restrict__ attn,
                       const float* __restrict__ norm2, float* __restrict__ y,
                       float* __restrict__ csum) {
  int blk = blockIdx.x;         // 512: b(8) x sc(64 chunks of 64)
  int b = blk >> 6;
  int sc = (blk & 63) * 64;
  __shared__ float coef[64];
  int tid = threadIdx.x;
  if (tid < 64) {
    int s = sc + tid;
    coef[tid] = attn[b * Sn + s] / fmaxf(1.f, sqrtf(norm2[b * Sn + s]));
  }
  __syncthreads();
  if (tid == 0) {
    float cs = 0.f;
    for (int i = 0; i < 64; ++i) cs += coef[i];
    atomicAdd(&csum[b], cs);
  }
  const u16* vbb = vb + ((size_t)b * Sn + sc) * Dn;
  int d0 = tid * 4;
  float a0 = 0.f, a1 = 0.f, a2 = 0.f, a3 = 0.f;
  for (int i = 0; i < 64; ++i) {
    float c = coef[i];
    u16x4 r = *reinterpret_cast<const u16x4*>(vbb + (size_t)i * Dn + d0);
    a0 = fmaf(c, bf2f(r[0]), a0); a1 = fmaf(c, bf2f(r[1]), a1);
    a2 = fmaf(c, bf2f(r[2]), a2); a3 = fmaf(c, bf2f(r[3]), a3);
  }
  atomicAdd(&y[b * Dn + d0 + 0], a0);
  atomicAdd(&y[b * Dn + d0 + 1], a1);
  atomicAdd(&y[b * Dn + d0 + 2], a2);
  atomicAdd(&y[b * Dn + d0 + 3], a3);
}

// ---------------- seed = y@Wv + csum*bv + 0.1*noise, split-K ----------------
__global__ void k_seed(const float* __restrict__ y, const float* __restrict__ wv,
                       const float* __restrict__ bv, const float* __restrict__ csum,
                       float* __restrict__ out_seed) {
  int blk = blockIdx.x;               // b(8) x jc(4) x dc(8)
  int b = blk >> 5, jc = (blk >> 3) & 3, dc = blk & 7;
  int j = jc * 256 + threadIdx.x;
  const float* yb = y + b * Dn;
  float acc = 0.f;
  int d0 = dc * 128;
  for (int d = d0; d < d0 + 128; ++d)
    acc = fmaf(yb[d], wv[(size_t)d * Kn + j], acc);
  if (dc == 0) {
    acc += csum[b] * bv[j];
    int t = b * Kn + j;
    uint32_t o0, o1;
    threefry2x32(0u, 1234u, 0u, (uint32_t)t, &o0, &o1);
    uint32_t bits = o0 ^ o1;
    float f = __uint_as_float((bits >> 9) | 0x3F800000u) - 1.0f;
    float lo = __uint_as_float(0xBF7FFFFFu);
    float u = f * (1.0f - lo) + lo;
    u = fmaxf(u, lo);
    acc += 1.41421356237f * erfinv_f(u) * 0.1f;
  }
  atomicAdd(&out_seed[b * Kn + j], acc);
}

extern "C" void kernel_launch(void* const* d_in, const int* in_sizes, int n_in,
                              void* d_out, int out_size, void* d_ws, size_t ws_size,
                              hipStream_t stream) {
  const float* q  = (const float*)d_in[0];
  const float* k  = (const float*)d_in[1];
  const float* v  = (const float*)d_in[2];
  const float* wq = (const float*)d_in[3];
  const float* bq = (const float*)d_in[4];
  const float* wk = (const float*)d_in[5];
  const float* bk = (const float*)d_in[6];
  const float* wv = (const float*)d_in[7];
  const float* bv = (const float*)d_in[8];
  float* out = (float*)d_out;
  float* ws = (float*)d_ws;

  // ws floats: fq[0,8192) g[8192,16384) cb[16384,16392) norm2[16896,49664)
  //            y[49664,57856) csum[57856,57864)
  // bytes: wvt @ [262144, 262144+2MB) ; vb @ [4MB, 4MB+64MB)
  float* fq    = ws;
  float* g     = ws + 8192;
  float* cb    = ws + 16384;
  float* norm2 = ws + 16896;
  float* y     = ws + 49664;
  float* csum  = ws + 57856;
  u16* wvt = (u16*)((char*)d_ws + 262144);
  u16* vb  = (u16*)((char*)d_ws + (4 << 20));

  hipMemsetAsync(ws, 0, 57864 * sizeof(float), stream);       // fq,g,cb,norm2,y,csum
  hipMemsetAsync(out, 0, 8192 * sizeof(float), stream);       // seed accum base
  k_fq  <<<256,   256, 0, stream>>>(q, wq, bq, fq);
  k_g   <<<2048,  256, 0, stream>>>(wk, fq, g);
  k_cb  <<<1,     512, 0, stream>>>(fq, bk, cb);
  k_twv <<<256,   256, 0, stream>>>(wv, wvt);
  k_attn<<<8192,  256, 0, stream>>>(k, g, cb, out + 8192);
  k_tv  <<<16384, 256, 0, stream>>>(v, vb);
  k_norm2<<<2048, 256, 0, stream>>>(vb, wvt, bv, norm2);
  k_wsum<<<512,   256, 0, stream>>>(vb, out + 8192, norm2, y, csum);
  k_seed<<<256,   256, 0, stream>>>(y, wv, bv, csum, out);
}